// Round 1
// baseline (539.066 us; speedup 1.0000x reference)
//
#include <hip/hip_runtime.h>

#define NEMB 512
#define EMB 64
#define DECAYF 0.99f
#define OMDF 0.01f
#define EPSF 1e-5f

// geometry: x is (32, 64, 64, 64) = (B, D, H, W)
#define HW 4096            // 64*64
#define BSTRIDE 262144     // 64*4096
// output layout (floats): result 8388608 | argmin 131072 | weight 32768 | cluster 512 | avg 32768

__global__ void wsq_kernel(const float* __restrict__ w, float* __restrict__ wsq) {
    int j = threadIdx.x;  // 512
    float s = 0.f;
#pragma unroll
    for (int d = 0; d < EMB; ++d) { float v = w[d * NEMB + j]; s = fmaf(v, v, s); }
    wsq[j] = s;
}

// One block = 2 h-rows = 128 tokens. 256 threads: tg = tid&31 (4 tokens), jq = tid>>5 (8 j's/chunk).
__global__ __launch_bounds__(256) void vq_main(
    const float* __restrict__ x, const float* __restrict__ w,
    const float* __restrict__ wsq,
    float* __restrict__ out_result, float* __restrict__ out_arg,
    float* __restrict__ cnt, float* __restrict__ es)
{
    __shared__ __align__(16) float xt[EMB * 128];   // 32 KB, xt[d][t]
    __shared__ __align__(16) float wl[4096];        // 16 KB, wl[d][j] chunk; reused for reduction
    __shared__ float xsq[128];
    __shared__ int   jmin_s[128];

    const int tid = threadIdx.x;
    const int blk = blockIdx.x;          // 1024 blocks
    const int b  = blk >> 5;
    const int h0 = (blk & 31) << 1;      // 2 rows per block
    const float* xbase = x + b * BSTRIDE + h0 * 64;

    // stage x tile: 64 rows x 128 tokens, rows contiguous in global (2 adjacent h-rows)
#pragma unroll
    for (int k = 0; k < 8; ++k) {
        int idx = tid + (k << 8);        // float4 index 0..2047
        int d = idx >> 5, q = idx & 31;
        float4 v = *(const float4*)(xbase + d * HW + (q << 2));
        *(float4*)(xt + d * 128 + (q << 2)) = v;
    }
    __syncthreads();

    if (tid < 128) {
        float s = 0.f;
#pragma unroll
        for (int d = 0; d < EMB; ++d) { float v = xt[d * 128 + tid]; s = fmaf(v, v, s); }
        xsq[tid] = s;
    }
    __syncthreads();

    const int tg = tid & 31;
    const int jq = tid >> 5;
    const int jbase = jq << 3;

    float xs[4];
    {
        float4 t4 = *(const float4*)(xsq + (tg << 2));
        xs[0] = t4.x; xs[1] = t4.y; xs[2] = t4.z; xs[3] = t4.w;
    }

    // per-thread top-2 per token (for f64 tie refinement)
    float b1[4], b2[4]; int j1a[4], j2a[4];
#pragma unroll
    for (int t = 0; t < 4; ++t) { b1[t] = 3.4e38f; b2[t] = 3.4e38f; j1a[t] = 0; j2a[t] = 0; }

    for (int c = 0; c < 8; ++c) {
        // stage 64-j weight chunk: wl[d][j], j contiguous
#pragma unroll
        for (int k = 0; k < 4; ++k) {
            int idx = tid + (k << 8);    // float4 index 0..1023
            int d = idx >> 4, q = idx & 15;
            float4 v = *(const float4*)(w + d * NEMB + (c << 6) + (q << 2));
            *(float4*)(wl + (d << 6) + (q << 2)) = v;
        }
        __syncthreads();

        float acc[8][4];
#pragma unroll
        for (int jj = 0; jj < 8; ++jj)
#pragma unroll
            for (int t = 0; t < 4; ++t) acc[jj][t] = 0.f;

#pragma unroll 8
        for (int d = 0; d < EMB; ++d) {
            float4 xv = *(const float4*)(xt + d * 128 + (tg << 2));
            float4 wa = *(const float4*)(wl + (d << 6) + jbase);
            float4 wb = *(const float4*)(wl + (d << 6) + jbase + 4);
            float xr[4] = {xv.x, xv.y, xv.z, xv.w};
            float wr[8] = {wa.x, wa.y, wa.z, wa.w, wb.x, wb.y, wb.z, wb.w};
#pragma unroll
            for (int jj = 0; jj < 8; ++jj)
#pragma unroll
                for (int t = 0; t < 4; ++t)
                    acc[jj][t] = fmaf(wr[jj], xr[t], acc[jj][t]);
        }

        int jc = (c << 6) + jbase;
#pragma unroll
        for (int jj = 0; jj < 8; ++jj) {
            int j = jc + jj;
            float wq = wsq[j];
#pragma unroll
            for (int t = 0; t < 4; ++t) {
                float s = (xs[t] - 2.f * acc[jj][t]) + wq;   // ||x||^2 - 2 x.w + ||w||^2
                if (s < b1[t])      { b2[t] = b1[t]; j2a[t] = j1a[t]; b1[t] = s; j1a[t] = j; }
                else if (s < b2[t]) { b2[t] = s; j2a[t] = j; }
            }
        }
        __syncthreads();
    }

    // cross-thread top-2 reduction, reusing wl as scratch (16 KB)
    float* rs1 = wl;
    int*   rj1 = (int*)(wl + 1024);
    float* rs2 = wl + 2048;
    int*   rj2 = (int*)(wl + 3072);
#pragma unroll
    for (int t = 0; t < 4; ++t) {
        int tok = (tg << 2) + t;
        rs1[tok * 8 + jq] = b1[t]; rj1[tok * 8 + jq] = j1a[t];
        rs2[tok * 8 + jq] = b2[t]; rj2[tok * 8 + jq] = j2a[t];
    }
    __syncthreads();

    if (tid < 128) {
        float S1 = 3.4e38f, S2 = 3.4e38f; int J1 = 0, J2 = 0;
#pragma unroll
        for (int k = 0; k < 8; ++k) {
            float sa = rs1[tid * 8 + k]; int ja = rj1[tid * 8 + k];
            float sb = rs2[tid * 8 + k]; int jb = rj2[tid * 8 + k];
#define UPD(s_, j_) do { \
            if (s_ < S1 || (s_ == S1 && j_ < J1)) { S2 = S1; J2 = J1; S1 = s_; J1 = j_; } \
            else if (s_ < S2 || (s_ == S2 && j_ < J2)) { S2 = s_; J2 = j_; } } while (0)
            UPD(sa, ja);
            UPD(sb, jb);
#undef UPD
        }

        int jm = J1;
        if (S2 - S1 < 1e-3f) {
            // near-tie: recompute the two candidates in f64 (exact decision wrt real arithmetic)
            double dot1 = 0.0, dot2 = 0.0, sq1 = 0.0, sq2 = 0.0;
            for (int d = 0; d < EMB; ++d) {
                double xv = (double)xt[d * 128 + tid];
                double w1 = (double)w[d * NEMB + J1];
                double w2 = (double)w[d * NEMB + J2];
                dot1 = fma(xv, w1, dot1); sq1 = fma(w1, w1, sq1);
                dot2 = fma(xv, w2, dot2); sq2 = fma(w2, w2, sq2);
            }
            double e1 = sq1 - 2.0 * dot1;
            double e2 = sq2 - 2.0 * dot2;
            if (e2 < e1 || (e2 == e1 && J2 < J1)) jm = J2;
        }
        jmin_s[tid] = jm;
        out_arg[b * HW + h0 * 64 + tid] = (float)jm;
        atomicAdd(&cnt[jm], 1.0f);
    }
    __syncthreads();

    // epilogue: quantized result (gather) + embed_sum scatter
    const int obase = b * BSTRIDE + h0 * 64;
#pragma unroll 4
    for (int i = 0; i < 32; ++i) {
        int idx = tid + (i << 8);        // 0..8191 = (d, t)
        int d = idx >> 7, t = idx & 127;
        int j = jmin_s[t];
        float xv = xt[d * 128 + t];
        out_result[obase + d * HW + t] = w[d * NEMB + j];
        atomicAdd(&es[d * NEMB + j], xv);
    }
}

// counts (in ncs_io) -> new_cluster_size (in place), n -> ws_n
__global__ void finalize_cs(const float* __restrict__ cs_in, float* __restrict__ ncs_io,
                            float* __restrict__ ws_n) {
    __shared__ float red[512];
    int j = threadIdx.x;
    float cval = ncs_io[j];
    float nidx = (cval == 0.f) ? 1.f : cval;
    float ncs = DECAYF * cs_in[j] + OMDF * nidx;
    ncs_io[j] = ncs;
    red[j] = ncs;
    __syncthreads();
    for (int s = 256; s > 0; s >>= 1) {
        if (j < s) red[j] += red[j + s];
        __syncthreads();
    }
    if (j == 0) ws_n[0] = red[0];
}

// es (in avg_io) + embed_avg -> new_embed_avg (in place) and new_weight
__global__ void finalize_w(const float* __restrict__ avg_in,
                           const float* __restrict__ ncs, const float* __restrict__ ws_n,
                           float* __restrict__ out_w, float* __restrict__ avg_io) {
    int d = blockIdx.x, j = threadIdx.x;
    float n = ws_n[0];
    float ncsj = ncs[j];
    float csj = (ncsj + EPSF) / (n + (float)NEMB * EPSF) * n;
    float esv = avg_io[d * NEMB + j];
    float navg = DECAYF * avg_in[d * NEMB + j] + OMDF * esv;
    avg_io[d * NEMB + j] = navg;
    out_w[d * NEMB + j] = navg / csj;
}

extern "C" void kernel_launch(void* const* d_in, const int* in_sizes, int n_in,
                              void* d_out, int out_size, void* d_ws, size_t ws_size,
                              hipStream_t stream) {
    (void)in_sizes; (void)n_in; (void)out_size; (void)ws_size;
    const float* x   = (const float*)d_in[0];
    const float* w   = (const float*)d_in[1];
    const float* cs  = (const float*)d_in[2];
    const float* avg = (const float*)d_in[3];

    float* out = (float*)d_out;
    float* out_result = out;                 // 8388608
    float* out_arg    = out + 8388608;       // 131072
    float* out_w      = out + 8519680;       // 32768
    float* out_ncs    = out + 8552448;       // 512  (counts accumulate here first)
    float* out_avg    = out + 8552960;       // 32768 (embed_sum accumulates here first)

    float* wsq  = (float*)d_ws;              // 512 floats
    float* ws_n = (float*)d_ws + 512;        // 1 float

    // zero the two accumulator output regions (contiguous: 512 + 32768 floats)
    hipMemsetAsync(out_ncs, 0, (size_t)33280 * sizeof(float), stream);
    wsq_kernel<<<1, 512, 0, stream>>>(w, wsq);
    vq_main<<<1024, 256, 0, stream>>>(x, w, wsq, out_result, out_arg, out_ncs, out_avg);
    finalize_cs<<<1, 512, 0, stream>>>(cs, out_ncs, ws_n);
    finalize_w<<<64, 512, 0, stream>>>(avg, out_ncs, ws_n, out_w, out_avg);
}